// Round 9
// baseline (109.826 us; speedup 1.0000x reference)
//
#include <hip/hip_runtime.h>

typedef __attribute__((ext_vector_type(8))) short bf16x8;
typedef __attribute__((ext_vector_type(4))) float f32x4;
typedef __attribute__((ext_vector_type(16))) float f32x16;
typedef __attribute__((ext_vector_type(4))) float fl4;
typedef __attribute__((ext_vector_type(8))) unsigned short u16x8;
typedef __attribute__((ext_vector_type(4))) unsigned short u16x4;
typedef __attribute__((ext_vector_type(2))) int i32x2;
typedef __attribute__((ext_vector_type(4))) int i32x4;

#define MFMA16(A,B,C) __builtin_amdgcn_mfma_f32_16x16x32_bf16((A),(B),(C),0,0,0)
#define MFMA32(A,B,C) __builtin_amdgcn_mfma_f32_32x32x16_bf16((A),(B),(C),0,0,0)

__device__ __forceinline__ unsigned short f2bf_bits(float x) {
  union { float f; unsigned u; } v; v.f = x;
  unsigned r = v.u + 0x7fffu + ((v.u >> 16) & 1u);  // RTNE
  return (unsigned short)(r >> 16);
}

__device__ __forceinline__ void gload_lds16(const void* g, void* l) {
  __builtin_amdgcn_global_load_lds((const __attribute__((address_space(1))) void*)g,
                                   (__attribute__((address_space(3))) void*)l, 16, 0, 0);
}

// read one 16B MFMA fragment from a 128B-row LDS tile with XOR swizzle
__device__ __forceinline__ bf16x8 lds_frag(const char* base, int row, int bir) {
  int off = (row << 7) + bir;
  off ^= (row & 7) << 4;
  return *(const bf16x8*)(base + off);
}

// pack two f32 to packed bf16 (lo = a, hi = b), RTNE
__device__ __forceinline__ int cvtpk_bf16(float a, float b) {
  int r; asm("v_cvt_pk_bf16_f32 %0, %1, %2" : "=v"(r) : "v"(a), "v"(b)); return r;
}

// swap a's upper-lane-half with b's lower-lane-half (v_permlane32_swap_b32)
__device__ __forceinline__ void plswap(int& a, int& b) {
#if __has_builtin(__builtin_amdgcn_permlane32_swap)
  i32x2 r = __builtin_amdgcn_permlane32_swap(a, b, false, false);
  a = r[0]; b = r[1];
#else
  asm volatile("s_nop 1\n\tv_permlane32_swap_b32 %0, %1" : "+v"(a), "+v"(b));
#endif
}

// ---------------- elementwise fp32 -> bf16, plus fused mask->bias (blocks >= 2048) ----------------
// mb = ((1-m)*(-5) - 4) * log2(e) = m*7.2134752 - 12.9842554
__global__ __launch_bounds__(256) void k_cvt(const float* __restrict__ src,
                                             unsigned short* __restrict__ dst, int n,
                                             const float* __restrict__ m,
                                             float* __restrict__ mb) {
  int bid = blockIdx.x;
  if (bid >= 2048) {
    int i = (bid - 2048) * 256 + threadIdx.x;
    mb[i] = fmaf(m[i], 7.2134752f, -12.9842554f);
    return;
  }
  int i = (bid * 256 + threadIdx.x) * 8;
  if (i >= n) return;
  fl4 a = *(const fl4*)(src + i);
  fl4 b = *(const fl4*)(src + i + 4);
  u16x8 o;
  o[0] = f2bf_bits(a[0]); o[1] = f2bf_bits(a[1]); o[2] = f2bf_bits(a[2]); o[3] = f2bf_bits(a[3]);
  o[4] = f2bf_bits(b[0]); o[5] = f2bf_bits(b[1]); o[6] = f2bf_bits(b[2]); o[7] = f2bf_bits(b[3]);
  *(u16x8*)(dst + i) = o;
}

// ---------------- transpose + convert, both weights in one launch ----------------
// blockIdx.x < 48: W_qkv [1024][3072] -> [3072][1024]; else W_proj [1024][1024] -> [1024][1024]
__global__ __launch_bounds__(256) void k_tcvt2(const float* __restrict__ wqkv,
                                               unsigned short* __restrict__ dqkv,
                                               const float* __restrict__ wproj,
                                               unsigned short* __restrict__ dproj) {
  __shared__ float tile[64][65];
  const int bx = blockIdx.x;
  const float* src; unsigned short* dst; int NCOL, nt;
  if (bx < 48) { src = wqkv; dst = dqkv; NCOL = 3072; nt = bx * 64; }
  else         { src = wproj; dst = dproj; NCOL = 1024; nt = (bx - 48) * 64; }
  const int kt = blockIdx.y * 64;
  const int t = threadIdx.x;
  {
    int r = t >> 2, c0 = (t & 3) * 16;
    const float* s = src + (size_t)(kt + r) * NCOL + nt + c0;
    #pragma unroll
    for (int j = 0; j < 4; ++j) {
      fl4 v = *(const fl4*)(s + j * 4);
      tile[r][c0 + j * 4 + 0] = v[0]; tile[r][c0 + j * 4 + 1] = v[1];
      tile[r][c0 + j * 4 + 2] = v[2]; tile[r][c0 + j * 4 + 3] = v[3];
    }
  }
  __syncthreads();
  {
    int n = t >> 2, kc = (t & 3) * 16;
    unsigned short* d = dst + (size_t)(nt + n) * 1024 + kt + kc;
    u16x8 o0, o1;
    #pragma unroll
    for (int j = 0; j < 8; ++j) o0[j] = f2bf_bits(tile[kc + j][n]);
    #pragma unroll
    for (int j = 0; j < 8; ++j) o1[j] = f2bf_bits(tile[kc + 8 + j][n]);
    *(u16x8*)d = o0;
    *(u16x8*)(d + 8) = o1;
  }
}

// ---------------- bf16 GEMM: C[M][Ncols] = A[M][1024] * Bt[Ncols][1024]^T ----------------
template <int MODE>
__global__ __launch_bounds__(256) void k_gemm(const unsigned short* __restrict__ A,
                                              const unsigned short* __restrict__ Bt,
                                              unsigned short* __restrict__ qp,
                                              unsigned short* __restrict__ kp,
                                              unsigned short* __restrict__ vtp,
                                              const float* __restrict__ bias,
                                              float* __restrict__ outp) {
  __shared__ char lA[16384], lB[16384];
  const int tid = threadIdx.x, lane = tid & 63, w = tid >> 6;
  const int wm = w >> 1, wn = w & 1;
  const int m0 = blockIdx.y * 128, n0 = blockIdx.x * 128;
  const char* Ab = (const char*)A + (size_t)m0 * 2048;
  const char* Bb = (const char*)Bt + (size_t)n0 * 2048;

  f32x4 acc[4][4];
  #pragma unroll
  for (int mi = 0; mi < 4; ++mi)
    #pragma unroll
    for (int ni = 0; ni < 4; ++ni) acc[mi][ni] = f32x4{0.f, 0.f, 0.f, 0.f};

  for (int kt = 0; kt < 16; ++kt) {
    #pragma unroll
    for (int i = 0; i < 4; ++i) {
      int c = i * 256 + tid;
      int row = c >> 3, cc = c & 7, ccs = cc ^ (row & 7);
      char* dstA = lA + (i * 256 + w * 64) * 16;
      char* dstB = lB + (i * 256 + w * 64) * 16;
      gload_lds16(Ab + (size_t)row * 2048 + kt * 128 + ccs * 16, dstA);
      gload_lds16(Bb + (size_t)row * 2048 + kt * 128 + ccs * 16, dstB);
    }
    __syncthreads();
    #pragma unroll
    for (int ks = 0; ks < 2; ++ks) {
      bf16x8 af[4], bfv[4];
      #pragma unroll
      for (int mi = 0; mi < 4; ++mi)
        af[mi] = lds_frag(lA, wm * 64 + mi * 16 + (lane & 15), ks * 64 + ((lane >> 4) << 4));
      #pragma unroll
      for (int ni = 0; ni < 4; ++ni)
        bfv[ni] = lds_frag(lB, wn * 64 + ni * 16 + (lane & 15), ks * 64 + ((lane >> 4) << 4));
      #pragma unroll
      for (int mi = 0; mi < 4; ++mi)
        #pragma unroll
        for (int ni = 0; ni < 4; ++ni)
          acc[mi][ni] = MFMA16(af[mi], bfv[ni], acc[mi][ni]);
    }
    __syncthreads();
  }

  if (MODE == 0) {
    #pragma unroll
    for (int mi = 0; mi < 4; ++mi) {
      int row0 = m0 + wm * 64 + mi * 16 + ((lane >> 4) << 2);
      int bb = row0 >> 10, nn0 = row0 & 1023;
      #pragma unroll
      for (int ni = 0; ni < 4; ++ni) {
        int col = n0 + wn * 64 + ni * 16 + (lane & 15);
        int tt = col >> 10, rem = col & 1023, h = rem >> 6, d = rem & 63;
        f32x4 a = acc[mi][ni];
        if (tt == 2) {
          u16x4 pv;
          pv[0] = f2bf_bits(a[0]); pv[1] = f2bf_bits(a[1]);
          pv[2] = f2bf_bits(a[2]); pv[3] = f2bf_bits(a[3]);
          *(u16x4*)(vtp + (((size_t)(bb * 16 + h) * 64 + d) << 10) + nn0) = pv;
        } else {
          unsigned short* dst = (tt == 0) ? qp : kp;
          size_t base = ((size_t)(bb * 16 + h)) << 16;
          #pragma unroll
          for (int r = 0; r < 4; ++r)
            dst[base + (size_t)(nn0 + r) * 64 + d] = f2bf_bits(a[r]);
        }
      }
    }
  } else {
    #pragma unroll
    for (int mi = 0; mi < 4; ++mi) {
      int row0 = m0 + wm * 64 + mi * 16 + ((lane >> 4) << 2);
      #pragma unroll
      for (int ni = 0; ni < 4; ++ni) {
        int col = n0 + wn * 64 + ni * 16 + (lane & 15);
        float bv = bias[col];
        f32x4 a = acc[mi][ni];
        #pragma unroll
        for (int r = 0; r < 4; ++r)
          outp[(size_t)(row0 + r) * 1024 + col] = a[r] + bv;
      }
    }
  }
}

// ---------------- flash attention: in-block split-K, 32x32 swapped-operand, in-reg softmax ----
// 256 thr = 4 waves over the same 64 q-rows. Wave-pair A (w0,w1) handles keys 0-511,
// pair B (w2,w3) keys 512-1023. Each step stages 32-key K/V tiles for BOTH pairs
// (coalesced gload_lds, swizzled), one barrier per step. Mask bias precomputed into
// exp2-domain (mbias) and applied in the exp fma. Partials combined via LDS.
// LDS buf layout (16KB per buffer, x2): [KA 4K][KB 4K][VA 4K][VB 4K]
//   K tile: 32 rows x 128B, slot s at row r holds global chunk s^(r&7)
//   V tile: 64 rows x 64B,  slot s at row r holds global chunk s^((r>>1)&3)
__global__ __launch_bounds__(256, 4) void k_attn(const unsigned short* __restrict__ qp,
                                                 const unsigned short* __restrict__ kp,
                                                 const unsigned short* __restrict__ vtp,
                                                 const float* __restrict__ mbias,
                                                 unsigned short* __restrict__ aop) {
  __shared__ __align__(16) char lds[32768];
  const int tid = threadIdx.x, lane = tid & 63, w = tid >> 6;
  const int hi = lane >> 5, lq = lane & 31;
  const int pair = w >> 1;
  // XCD swizzle: all 16 q-chunk blocks of a head on one XCD; 8 heads/XCD
  const int g = blockIdx.x;
  const int bh = (g & 7) * 8 + (g >> 7);
  const int qc = (g >> 3) & 15;
  const int b = bh >> 4, h = bh & 15;
  const char* kb = (const char*)(kp + ((size_t)bh << 16));
  const char* vb = (const char*)(vtp + ((size_t)bh << 16));
  const unsigned short* qh = qp + ((size_t)bh << 16);
  const float* mrow = mbias + b * 1024 + pair * 512;
  const int q0 = qc * 64 + (w & 1) * 32;

  // ---- hoisted staging addresses (per thread, constant over steps) ----
  const int krow = tid >> 3, kslot = tid & 7;
  const int kcc = kslot ^ (krow & 7);
  const char* gKA = kb + (size_t)krow * 128 + kcc * 16;     // + t*4096
  const char* gKB = gKA + 512 * 128;
  const int vrow = tid >> 2, vslot = tid & 3;
  const int vcc = vslot ^ ((vrow >> 1) & 3);
  const char* gVA = vb + (size_t)vrow * 2048 + vcc * 16;    // + t*64
  const char* gVB = gVA + 512 * 2;
  char* const dK = lds + tid * 16;          // + buf*16384 (KB at +4096)
  char* const dV = lds + 8192 + tid * 16;   // + buf*16384 (VB at +4096)

  // ---- hoisted fragment-read offsets ----
  const char* const myK = lds + pair * 4096;
  const char* const myV = lds + 8192 + pair * 4096;
  int kfo[4], vfo[4];
  #pragma unroll
  for (int dc = 0; dc < 4; ++dc)
    kfo[dc] = lq * 128 + (((dc << 1) | hi) ^ (lq & 7)) * 16;
  #pragma unroll
  for (int ks = 0; ks < 2; ++ks)
    #pragma unroll
    for (int nb = 0; nb < 2; ++nb) {
      int row = nb * 32 + lq;
      vfo[ks * 2 + nb] = row * 64 + (((ks << 1) | hi) ^ ((row >> 1) & 3)) * 16;
    }

  // Q B-frags: B[kd = dc*16 + hi*8 + j][q = lq]
  bf16x8 qB[4];
  #pragma unroll
  for (int dc = 0; dc < 4; ++dc)
    qB[dc] = *(const bf16x8*)(qh + (q0 + lq) * 64 + dc * 16 + hi * 8);

  f32x16 O0, O1;
  #pragma unroll
  for (int i = 0; i < 16; ++i) { O0[i] = 0.f; O1[i] = 0.f; }
  float lsA = 0.f, lsB = 0.f;

#define STAGE(BUF, T)                                                          \
  do {                                                                         \
    gload_lds16(gKA + (T) * 4096, dK + (BUF) * 16384);                         \
    gload_lds16(gKB + (T) * 4096, dK + (BUF) * 16384 + 4096);                  \
    gload_lds16(gVA + (T) * 64,   dV + (BUF) * 16384);                         \
    gload_lds16(gVB + (T) * 64,   dV + (BUF) * 16384 + 4096);                  \
  } while (0)

#define STEP(BUF, T, LAST)                                                     \
  do {                                                                         \
    fl4 mw[4];                                                                 \
    _Pragma("unroll") for (int g4 = 0; g4 < 4; ++g4)                           \
      mw[g4] = *(const fl4*)(mrow + (T) * 32 + g4 * 8 + hi * 4);               \
    if (!(LAST)) STAGE((BUF) ^ 1, (T) + 1);                                    \
    const char* K = myK + (BUF) * 16384;                                       \
    const char* V = myV + (BUF) * 16384;                                       \
    f32x16 acc;                                                                \
    _Pragma("unroll") for (int i = 0; i < 16; ++i) acc[i] = 0.f;               \
    __builtin_amdgcn_s_setprio(1);                                             \
    _Pragma("unroll") for (int dc = 0; dc < 4; ++dc) {                         \
      bf16x8 kf = *(const bf16x8*)(K + kfo[dc]);                               \
      acc = MFMA32(kf, qB[dc], acc);                                           \
    }                                                                          \
    __builtin_amdgcn_s_setprio(0);                                             \
    float p[16];                                                               \
    _Pragma("unroll") for (int r = 0; r < 16; ++r) {                           \
      p[r] = exp2f(fmaf(acc[r], 0.18033688f, mw[r >> 2][r & 3]));              \
      if (r & 1) lsB += p[r]; else lsA += p[r];                                \
    }                                                                          \
    int X0 = cvtpk_bf16(p[0], p[1]),   X1 = cvtpk_bf16(p[2], p[3]);            \
    int Y0 = cvtpk_bf16(p[4], p[5]),   Y1 = cvtpk_bf16(p[6], p[7]);            \
    int Z0 = cvtpk_bf16(p[8], p[9]),   Z1 = cvtpk_bf16(p[10], p[11]);          \
    int W0 = cvtpk_bf16(p[12], p[13]), W1 = cvtpk_bf16(p[14], p[15]);          \
    plswap(X0, Y0); plswap(X1, Y1);                                            \
    plswap(Z0, W0); plswap(Z1, W1);                                            \
    i32x4 pa0v = {X0, X1, Y0, Y1};                                             \
    i32x4 pa1v = {Z0, Z1, W0, W1};                                             \
    const bf16x8 PA0 = __builtin_bit_cast(bf16x8, pa0v);                       \
    const bf16x8 PA1 = __builtin_bit_cast(bf16x8, pa1v);                       \
    bf16x8 va0 = *(const bf16x8*)(V + vfo[0]);                                 \
    bf16x8 va1 = *(const bf16x8*)(V + vfo[1]);                                 \
    bf16x8 vb0 = *(const bf16x8*)(V + vfo[2]);                                 \
    bf16x8 vb1 = *(const bf16x8*)(V + vfo[3]);                                 \
    __builtin_amdgcn_s_setprio(1);                                             \
    O0 = MFMA32(PA0, va0, O0);                                                 \
    O1 = MFMA32(PA0, va1, O1);                                                 \
    O0 = MFMA32(PA1, vb0, O0);                                                 \
    O1 = MFMA32(PA1, vb1, O1);                                                 \
    __builtin_amdgcn_s_setprio(0);                                             \
    __syncthreads();                                                           \
  } while (0)

  STAGE(0, 0);
  __syncthreads();
  for (int tt = 0; tt < 8; ++tt) {
    STEP(0, 2 * tt, 0);
    STEP(1, 2 * tt + 1, tt == 7);
  }
#undef STEP
#undef STAGE

  // ---- combine the two key-halves through LDS, then normalize + store ----
  float lsum = lsA + lsB;
  float tot = lsum + __shfl_xor(lsum, 32);
  float* fx = (float*)lds;
  if (pair == 1) {
    int base = (w - 2) * 64 * 34 + lane * 34;
    #pragma unroll
    for (int r = 0; r < 16; ++r) { fx[base + r] = O0[r]; fx[base + 16 + r] = O1[r]; }
    fx[base + 32] = tot;
  }
  __syncthreads();
  if (pair == 0) {
    int base = w * 64 * 34 + lane * 34;
    float invT = 1.0f / (tot + fx[base + 32]);
    #pragma unroll
    for (int r = 0; r < 16; ++r) {
      int qr = (r & 3) + 8 * (r >> 2) + 4 * hi;
      float iv = __shfl(invT, qr);
      float o0 = (O0[r] + fx[base + r]) * iv;
      float o1 = (O1[r] + fx[base + 16 + r]) * iv;
      size_t ob = (size_t)(b * 1024 + q0 + qr) * 1024 + h * 64 + lq;
      aop[ob] = f2bf_bits(o0);
      aop[ob + 32] = f2bf_bits(o1);
    }
  }
}

extern "C" void kernel_launch(void* const* d_in, const int* in_sizes, int n_in,
                              void* d_out, int out_size, void* d_ws, size_t ws_size,
                              hipStream_t stream) {
  const float* x     = (const float*)d_in[0];
  const float* mask  = (const float*)d_in[1];
  const float* wqkv  = (const float*)d_in[2];
  const float* wproj = (const float*)d_in[3];
  const float* bproj = (const float*)d_in[4];
  float* out = (float*)d_out;

  char* ws = (char*)d_ws;
  unsigned short* xb     = (unsigned short*)(ws);                 //  8 MB  x bf16 [4096][1024]
  unsigned short* wqkvt  = (unsigned short*)(ws + 8388608);       //  6 MB  W_qkv^T bf16 [3072][1024]
  unsigned short* wprojt = (unsigned short*)(ws + 14680064);      //  2 MB  W_proj^T bf16 [1024][1024]
  unsigned short* qbuf   = (unsigned short*)(ws + 16777216);      //  8 MB  q [B,H,N,D]
  unsigned short* kbuf   = (unsigned short*)(ws + 25165824);      //  8 MB  k [B,H,N,D]
  unsigned short* vtbuf  = (unsigned short*)(ws + 33554432);      //  8 MB  v^T [B,H,D,N]
  unsigned short* aobuf  = (unsigned short*)(ws + 41943040);      //  8 MB  attn out bf16 [4096][1024]
  float*          mbias  = (float*)(ws + 50331648);               // 16 KB  mask bias (exp2 domain)

  k_cvt<<<dim3(2064), dim3(256), 0, stream>>>(x, xb, 4194304, mask, mbias);
  k_tcvt2<<<dim3(64, 16), dim3(256), 0, stream>>>(wqkv, wqkvt, wproj, wprojt);
  k_gemm<0><<<dim3(24, 32), dim3(256), 0, stream>>>(xb, wqkvt, qbuf, kbuf, vtbuf, nullptr, nullptr);
  k_attn<<<dim3(1024), dim3(256), 0, stream>>>(qbuf, kbuf, vtbuf, mbias, aobuf);
  k_gemm<1><<<dim3(8, 32), dim3(256), 0, stream>>>(aobuf, wprojt, nullptr, nullptr, nullptr, bproj, out);
}

// Round 10
// 106.202 us; speedup vs baseline: 1.0341x; 1.0341x over previous
//
#include <hip/hip_runtime.h>

typedef __attribute__((ext_vector_type(8))) short bf16x8;
typedef __attribute__((ext_vector_type(4))) float f32x4;
typedef __attribute__((ext_vector_type(16))) float f32x16;
typedef __attribute__((ext_vector_type(4))) float fl4;
typedef __attribute__((ext_vector_type(8))) unsigned short u16x8;
typedef __attribute__((ext_vector_type(4))) unsigned short u16x4;
typedef __attribute__((ext_vector_type(2))) int i32x2;
typedef __attribute__((ext_vector_type(4))) int i32x4;

#define MFMA16(A,B,C) __builtin_amdgcn_mfma_f32_16x16x32_bf16((A),(B),(C),0,0,0)
#define MFMA32(A,B,C) __builtin_amdgcn_mfma_f32_32x32x16_bf16((A),(B),(C),0,0,0)

__device__ __forceinline__ unsigned short f2bf_bits(float x) {
  union { float f; unsigned u; } v; v.f = x;
  unsigned r = v.u + 0x7fffu + ((v.u >> 16) & 1u);  // RTNE
  return (unsigned short)(r >> 16);
}

__device__ __forceinline__ void gload_lds16(const void* g, void* l) {
  __builtin_amdgcn_global_load_lds((const __attribute__((address_space(1))) void*)g,
                                   (__attribute__((address_space(3))) void*)l, 16, 0, 0);
}

// read one 16B MFMA fragment from a 128B-row LDS tile with XOR swizzle
__device__ __forceinline__ bf16x8 lds_frag(const char* base, int row, int bir) {
  int off = (row << 7) + bir;
  off ^= (row & 7) << 4;
  return *(const bf16x8*)(base + off);
}

// pack two f32 to packed bf16 (lo = a, hi = b), RTNE
__device__ __forceinline__ int cvtpk_bf16(float a, float b) {
  int r; asm("v_cvt_pk_bf16_f32 %0, %1, %2" : "=v"(r) : "v"(a), "v"(b)); return r;
}

// swap a's upper-lane-half with b's lower-lane-half (v_permlane32_swap_b32)
__device__ __forceinline__ void plswap(int& a, int& b) {
#if __has_builtin(__builtin_amdgcn_permlane32_swap)
  i32x2 r = __builtin_amdgcn_permlane32_swap(a, b, false, false);
  a = r[0]; b = r[1];
#else
  asm volatile("s_nop 1\n\tv_permlane32_swap_b32 %0, %1" : "+v"(a), "+v"(b));
#endif
}

// ---------------- elementwise fp32 -> bf16 ----------------
__global__ __launch_bounds__(256) void k_cvt(const float* __restrict__ src,
                                             unsigned short* __restrict__ dst, int n) {
  int i = (blockIdx.x * 256 + threadIdx.x) * 8;
  if (i >= n) return;
  fl4 a = *(const fl4*)(src + i);
  fl4 b = *(const fl4*)(src + i + 4);
  u16x8 o;
  o[0] = f2bf_bits(a[0]); o[1] = f2bf_bits(a[1]); o[2] = f2bf_bits(a[2]); o[3] = f2bf_bits(a[3]);
  o[4] = f2bf_bits(b[0]); o[5] = f2bf_bits(b[1]); o[6] = f2bf_bits(b[2]); o[7] = f2bf_bits(b[3]);
  *(u16x8*)(dst + i) = o;
}

// ---------------- transpose + convert, both weights in one launch ----------------
// blockIdx.x < 48: W_qkv [1024][3072] -> [3072][1024]; else W_proj [1024][1024] -> [1024][1024]
__global__ __launch_bounds__(256) void k_tcvt2(const float* __restrict__ wqkv,
                                               unsigned short* __restrict__ dqkv,
                                               const float* __restrict__ wproj,
                                               unsigned short* __restrict__ dproj) {
  __shared__ float tile[64][65];
  const int bx = blockIdx.x;
  const float* src; unsigned short* dst; int NCOL, nt;
  if (bx < 48) { src = wqkv; dst = dqkv; NCOL = 3072; nt = bx * 64; }
  else         { src = wproj; dst = dproj; NCOL = 1024; nt = (bx - 48) * 64; }
  const int kt = blockIdx.y * 64;
  const int t = threadIdx.x;
  {
    int r = t >> 2, c0 = (t & 3) * 16;
    const float* s = src + (size_t)(kt + r) * NCOL + nt + c0;
    #pragma unroll
    for (int j = 0; j < 4; ++j) {
      fl4 v = *(const fl4*)(s + j * 4);
      tile[r][c0 + j * 4 + 0] = v[0]; tile[r][c0 + j * 4 + 1] = v[1];
      tile[r][c0 + j * 4 + 2] = v[2]; tile[r][c0 + j * 4 + 3] = v[3];
    }
  }
  __syncthreads();
  {
    int n = t >> 2, kc = (t & 3) * 16;
    unsigned short* d = dst + (size_t)(nt + n) * 1024 + kt + kc;
    u16x8 o0, o1;
    #pragma unroll
    for (int j = 0; j < 8; ++j) o0[j] = f2bf_bits(tile[kc + j][n]);
    #pragma unroll
    for (int j = 0; j < 8; ++j) o1[j] = f2bf_bits(tile[kc + 8 + j][n]);
    *(u16x8*)d = o0;
    *(u16x8*)(d + 8) = o1;
  }
}

// ---------------- bf16 GEMM: C[M][Ncols] = A[M][1024] * Bt[Ncols][1024]^T ----------------
template <int MODE>
__global__ __launch_bounds__(256) void k_gemm(const unsigned short* __restrict__ A,
                                              const unsigned short* __restrict__ Bt,
                                              unsigned short* __restrict__ qp,
                                              unsigned short* __restrict__ kp,
                                              unsigned short* __restrict__ vtp,
                                              const float* __restrict__ bias,
                                              float* __restrict__ outp) {
  __shared__ char lA[16384], lB[16384];
  const int tid = threadIdx.x, lane = tid & 63, w = tid >> 6;
  const int wm = w >> 1, wn = w & 1;
  const int m0 = blockIdx.y * 128, n0 = blockIdx.x * 128;
  const char* Ab = (const char*)A + (size_t)m0 * 2048;
  const char* Bb = (const char*)Bt + (size_t)n0 * 2048;

  f32x4 acc[4][4];
  #pragma unroll
  for (int mi = 0; mi < 4; ++mi)
    #pragma unroll
    for (int ni = 0; ni < 4; ++ni) acc[mi][ni] = f32x4{0.f, 0.f, 0.f, 0.f};

  for (int kt = 0; kt < 16; ++kt) {
    #pragma unroll
    for (int i = 0; i < 4; ++i) {
      int c = i * 256 + tid;
      int row = c >> 3, cc = c & 7, ccs = cc ^ (row & 7);
      char* dstA = lA + (i * 256 + w * 64) * 16;
      char* dstB = lB + (i * 256 + w * 64) * 16;
      gload_lds16(Ab + (size_t)row * 2048 + kt * 128 + ccs * 16, dstA);
      gload_lds16(Bb + (size_t)row * 2048 + kt * 128 + ccs * 16, dstB);
    }
    __syncthreads();
    #pragma unroll
    for (int ks = 0; ks < 2; ++ks) {
      bf16x8 af[4], bfv[4];
      #pragma unroll
      for (int mi = 0; mi < 4; ++mi)
        af[mi] = lds_frag(lA, wm * 64 + mi * 16 + (lane & 15), ks * 64 + ((lane >> 4) << 4));
      #pragma unroll
      for (int ni = 0; ni < 4; ++ni)
        bfv[ni] = lds_frag(lB, wn * 64 + ni * 16 + (lane & 15), ks * 64 + ((lane >> 4) << 4));
      #pragma unroll
      for (int mi = 0; mi < 4; ++mi)
        #pragma unroll
        for (int ni = 0; ni < 4; ++ni)
          acc[mi][ni] = MFMA16(af[mi], bfv[ni], acc[mi][ni]);
    }
    __syncthreads();
  }

  if (MODE == 0) {
    #pragma unroll
    for (int mi = 0; mi < 4; ++mi) {
      int row0 = m0 + wm * 64 + mi * 16 + ((lane >> 4) << 2);
      int bb = row0 >> 10, nn0 = row0 & 1023;
      #pragma unroll
      for (int ni = 0; ni < 4; ++ni) {
        int col = n0 + wn * 64 + ni * 16 + (lane & 15);
        int tt = col >> 10, rem = col & 1023, h = rem >> 6, d = rem & 63;
        f32x4 a = acc[mi][ni];
        if (tt == 2) {
          u16x4 pv;
          pv[0] = f2bf_bits(a[0]); pv[1] = f2bf_bits(a[1]);
          pv[2] = f2bf_bits(a[2]); pv[3] = f2bf_bits(a[3]);
          *(u16x4*)(vtp + (((size_t)(bb * 16 + h) * 64 + d) << 10) + nn0) = pv;
        } else {
          unsigned short* dst = (tt == 0) ? qp : kp;
          size_t base = ((size_t)(bb * 16 + h)) << 16;
          #pragma unroll
          for (int r = 0; r < 4; ++r)
            dst[base + (size_t)(nn0 + r) * 64 + d] = f2bf_bits(a[r]);
        }
      }
    }
  } else {
    #pragma unroll
    for (int mi = 0; mi < 4; ++mi) {
      int row0 = m0 + wm * 64 + mi * 16 + ((lane >> 4) << 2);
      #pragma unroll
      for (int ni = 0; ni < 4; ++ni) {
        int col = n0 + wn * 64 + ni * 16 + (lane & 15);
        float bv = bias[col];
        f32x4 a = acc[mi][ni];
        #pragma unroll
        for (int r = 0; r < 4; ++r)
          outp[(size_t)(row0 + r) * 1024 + col] = a[r] + bv;
      }
    }
  }
}

// ---------------- flash attention: in-block split-K, 32x32 swapped-operand, in-reg softmax ----
// r7 structure: 256 thr = 4 waves over the same 64 q-rows. Wave-pair A (w0,w1) keys 0-511,
// pair B (w2,w3) keys 512-1023. Each step stages 32-key K/V tiles for BOTH pairs
// (coalesced gload_lds, swizzled), one barrier per step; mask via rank-1 bias MFMA with
// ALL mask loads hoisted to block start (bws[16] in registers, loop fully unrolled so
// indexing stays static). Partials combined via LDS.
// LDS buf layout (16KB per buffer, x2): [KA 4K][KB 4K][VA 4K][VB 4K]
//   K tile: 32 rows x 128B, slot s at row r holds global chunk s^(r&7)
//   V tile: 64 rows x 64B,  slot s at row r holds global chunk s^((r>>1)&3)
__global__ __launch_bounds__(256, 4) void k_attn(const unsigned short* __restrict__ qp,
                                                 const unsigned short* __restrict__ kp,
                                                 const unsigned short* __restrict__ vtp,
                                                 const float* __restrict__ mask,
                                                 unsigned short* __restrict__ aop) {
  __shared__ __align__(16) char lds[32768];
  const int tid = threadIdx.x, lane = tid & 63, w = tid >> 6;
  const int hi = lane >> 5, lq = lane & 31;
  const int pair = w >> 1;
  // XCD swizzle: all 16 q-chunk blocks of a head on one XCD; 8 heads/XCD
  const int g = blockIdx.x;
  const int bh = (g & 7) * 8 + (g >> 7);
  const int qc = (g >> 3) & 15;
  const int b = bh >> 4, h = bh & 15;
  const char* kb = (const char*)(kp + ((size_t)bh << 16));
  const char* vb = (const char*)(vtp + ((size_t)bh << 16));
  const unsigned short* qh = qp + ((size_t)bh << 16);
  const float* mrow = mask + b * 1024 + pair * 512;
  const int q0 = qc * 64 + (w & 1) * 32;

  // ---- hoisted staging addresses (per thread, constant over steps) ----
  const int krow = tid >> 3, kslot = tid & 7;
  const int kcc = kslot ^ (krow & 7);
  const char* gKA = kb + (size_t)krow * 128 + kcc * 16;     // + t*4096
  const char* gKB = gKA + 512 * 128;
  const int vrow = tid >> 2, vslot = tid & 3;
  const int vcc = vslot ^ ((vrow >> 1) & 3);
  const char* gVA = vb + (size_t)vrow * 2048 + vcc * 16;    // + t*64
  const char* gVB = gVA + 512 * 2;
  char* const dK = lds + tid * 16;          // + buf*16384 (KB at +4096)
  char* const dV = lds + 8192 + tid * 16;   // + buf*16384 (VB at +4096)

  // ---- hoisted fragment-read offsets ----
  const char* const myK = lds + pair * 4096;
  const char* const myV = lds + 8192 + pair * 4096;
  int kfo[4], vfo[4];
  #pragma unroll
  for (int dc = 0; dc < 4; ++dc)
    kfo[dc] = lq * 128 + (((dc << 1) | hi) ^ (lq & 7)) * 16;
  #pragma unroll
  for (int ks = 0; ks < 2; ++ks)
    #pragma unroll
    for (int nb = 0; nb < 2; ++nb) {
      int row = nb * 32 + lq;
      vfo[ks * 2 + nb] = row * 64 + (((ks << 1) | hi) ^ ((row >> 1) & 3)) * 16;
    }

  // ---- hoist ALL mask loads out of the K-loop: bias-MFMA A-words for each step ----
  // bias adds (1-mask)*(-40) in pre-scale units; exact 0 contribution when mask==1
  int bws[16];
  #pragma unroll
  for (int t2 = 0; t2 < 16; ++t2) {
    float mv = mrow[t2 * 32 + lq];
    bws[t2] = (hi == 0) ? (int)f2bf_bits((1.0f - mv) * -40.0f) : 0;
  }

  // Q B-frags: B[kd = dc*16 + hi*8 + j][q = lq]
  bf16x8 qB[4];
  #pragma unroll
  for (int dc = 0; dc < 4; ++dc)
    qB[dc] = *(const bf16x8*)(qh + (q0 + lq) * 64 + dc * 16 + hi * 8);

  // ones B-frag for the bias MFMA: B[0][q] = 1
  i32x4 onesw = {hi == 0 ? 0x3F80 : 0, 0, 0, 0};
  const bf16x8 onesB = __builtin_bit_cast(bf16x8, onesw);

  f32x16 O0, O1;
  #pragma unroll
  for (int i = 0; i < 16; ++i) { O0[i] = 0.f; O1[i] = 0.f; }
  float lsum = 0.f;

#define STAGE(BUF, T)                                                          \
  do {                                                                         \
    gload_lds16(gKA + (T) * 4096, dK + (BUF) * 16384);                         \
    gload_lds16(gKB + (T) * 4096, dK + (BUF) * 16384 + 4096);                  \
    gload_lds16(gVA + (T) * 64,   dV + (BUF) * 16384);                         \
    gload_lds16(gVB + (T) * 64,   dV + (BUF) * 16384 + 4096);                  \
  } while (0)

#define STEP(BUF, T, LAST)                                                     \
  do {                                                                         \
    if (!(LAST)) STAGE((BUF) ^ 1, (T) + 1);                                    \
    const char* K = myK + (BUF) * 16384;                                       \
    const char* V = myV + (BUF) * 16384;                                       \
    f32x16 acc;                                                                \
    _Pragma("unroll") for (int i = 0; i < 16; ++i) acc[i] = 0.f;               \
    __builtin_amdgcn_s_setprio(1);                                             \
    _Pragma("unroll") for (int dc = 0; dc < 4; ++dc) {                         \
      bf16x8 kf = *(const bf16x8*)(K + kfo[dc]);                               \
      acc = MFMA32(kf, qB[dc], acc);                                           \
    }                                                                          \
    __builtin_amdgcn_s_setprio(0);                                             \
    {                                                                          \
      i32x4 bwv = {bws[T], 0, 0, 0};                                           \
      acc = MFMA32(__builtin_bit_cast(bf16x8, bwv), onesB, acc);               \
    }                                                                          \
    float p[16];                                                               \
    _Pragma("unroll") for (int r = 0; r < 16; ++r) {                           \
      p[r] = exp2f(fmaf(acc[r], 0.18033688f, -5.7707802f));                    \
      lsum += p[r];                                                            \
    }                                                                          \
    int X0 = cvtpk_bf16(p[0], p[1]),   X1 = cvtpk_bf16(p[2], p[3]);            \
    int Y0 = cvtpk_bf16(p[4], p[5]),   Y1 = cvtpk_bf16(p[6], p[7]);            \
    int Z0 = cvtpk_bf16(p[8], p[9]),   Z1 = cvtpk_bf16(p[10], p[11]);          \
    int W0 = cvtpk_bf16(p[12], p[13]), W1 = cvtpk_bf16(p[14], p[15]);          \
    plswap(X0, Y0); plswap(X1, Y1);                                            \
    plswap(Z0, W0); plswap(Z1, W1);                                            \
    i32x4 pa0v = {X0, X1, Y0, Y1};                                             \
    i32x4 pa1v = {Z0, Z1, W0, W1};                                             \
    const bf16x8 PA0 = __builtin_bit_cast(bf16x8, pa0v);                       \
    const bf16x8 PA1 = __builtin_bit_cast(bf16x8, pa1v);                       \
    bf16x8 va0 = *(const bf16x8*)(V + vfo[0]);                                 \
    bf16x8 va1 = *(const bf16x8*)(V + vfo[1]);                                 \
    bf16x8 vb0 = *(const bf16x8*)(V + vfo[2]);                                 \
    bf16x8 vb1 = *(const bf16x8*)(V + vfo[3]);                                 \
    __builtin_amdgcn_s_setprio(1);                                             \
    O0 = MFMA32(PA0, va0, O0);                                                 \
    O1 = MFMA32(PA0, va1, O1);                                                 \
    O0 = MFMA32(PA1, vb0, O0);                                                 \
    O1 = MFMA32(PA1, vb1, O1);                                                 \
    __builtin_amdgcn_s_setprio(0);                                             \
    __syncthreads();                                                           \
  } while (0)

  STAGE(0, 0);
  __syncthreads();
  #pragma unroll
  for (int tt = 0; tt < 8; ++tt) {
    STEP(0, 2 * tt, 0);
    STEP(1, 2 * tt + 1, tt == 7);
  }
#undef STEP
#undef STAGE

  // ---- combine the two key-halves through LDS, then normalize + store ----
  float tot = lsum + __shfl_xor(lsum, 32);
  float* fx = (float*)lds;
  if (pair == 1) {
    int base = (w - 2) * 64 * 34 + lane * 34;
    #pragma unroll
    for (int r = 0; r < 16; ++r) { fx[base + r] = O0[r]; fx[base + 16 + r] = O1[r]; }
    fx[base + 32] = tot;
  }
  __syncthreads();
  if (pair == 0) {
    int base = w * 64 * 34 + lane * 34;
    float invT = 1.0f / (tot + fx[base + 32]);
    #pragma unroll
    for (int r = 0; r < 16; ++r) {
      int qr = (r & 3) + 8 * (r >> 2) + 4 * hi;
      float iv = __shfl(invT, qr);
      float o0 = (O0[r] + fx[base + r]) * iv;
      float o1 = (O1[r] + fx[base + 16 + r]) * iv;
      size_t ob = (size_t)(b * 1024 + q0 + qr) * 1024 + h * 64 + lq;
      aop[ob] = f2bf_bits(o0);
      aop[ob + 32] = f2bf_bits(o1);
    }
  }
}

extern "C" void kernel_launch(void* const* d_in, const int* in_sizes, int n_in,
                              void* d_out, int out_size, void* d_ws, size_t ws_size,
                              hipStream_t stream) {
  const float* x     = (const float*)d_in[0];
  const float* mask  = (const float*)d_in[1];
  const float* wqkv  = (const float*)d_in[2];
  const float* wproj = (const float*)d_in[3];
  const float* bproj = (const float*)d_in[4];
  float* out = (float*)d_out;

  char* ws = (char*)d_ws;
  unsigned short* xb     = (unsigned short*)(ws);                 //  8 MB  x bf16 [4096][1024]
  unsigned short* wqkvt  = (unsigned short*)(ws + 8388608);       //  6 MB  W_qkv^T bf16 [3072][1024]
  unsigned short* wprojt = (unsigned short*)(ws + 14680064);      //  2 MB  W_proj^T bf16 [1024][1024]
  unsigned short* qbuf   = (unsigned short*)(ws + 16777216);      //  8 MB  q [B,H,N,D]
  unsigned short* kbuf   = (unsigned short*)(ws + 25165824);      //  8 MB  k [B,H,N,D]
  unsigned short* vtbuf  = (unsigned short*)(ws + 33554432);      //  8 MB  v^T [B,H,D,N]
  unsigned short* aobuf  = (unsigned short*)(ws + 41943040);      //  8 MB  attn out bf16 [4096][1024]

  k_cvt<<<dim3(2048), dim3(256), 0, stream>>>(x, xb, 4194304);
  k_tcvt2<<<dim3(64, 16), dim3(256), 0, stream>>>(wqkv, wqkvt, wproj, wprojt);
  k_gemm<0><<<dim3(24, 32), dim3(256), 0, stream>>>(xb, wqkvt, qbuf, kbuf, vtbuf, nullptr, nullptr);
  k_attn<<<dim3(1024), dim3(256), 0, stream>>>(qbuf, kbuf, vtbuf, mask, aobuf);
  k_gemm<1><<<dim3(8, 32), dim3(256), 0, stream>>>(aobuf, wprojt, nullptr, nullptr, nullptr, bproj, out);
}

// Round 11
// 105.789 us; speedup vs baseline: 1.0382x; 1.0039x over previous
//
#include <hip/hip_runtime.h>

typedef __attribute__((ext_vector_type(8))) short bf16x8;
typedef __attribute__((ext_vector_type(4))) float f32x4;
typedef __attribute__((ext_vector_type(16))) float f32x16;
typedef __attribute__((ext_vector_type(4))) float fl4;
typedef __attribute__((ext_vector_type(8))) unsigned short u16x8;
typedef __attribute__((ext_vector_type(4))) unsigned short u16x4;
typedef __attribute__((ext_vector_type(2))) int i32x2;
typedef __attribute__((ext_vector_type(4))) int i32x4;

#define MFMA16(A,B,C) __builtin_amdgcn_mfma_f32_16x16x32_bf16((A),(B),(C),0,0,0)
#define MFMA32(A,B,C) __builtin_amdgcn_mfma_f32_32x32x16_bf16((A),(B),(C),0,0,0)

__device__ __forceinline__ unsigned short f2bf_bits(float x) {
  union { float f; unsigned u; } v; v.f = x;
  unsigned r = v.u + 0x7fffu + ((v.u >> 16) & 1u);  // RTNE
  return (unsigned short)(r >> 16);
}

__device__ __forceinline__ void gload_lds16(const void* g, void* l) {
  __builtin_amdgcn_global_load_lds((const __attribute__((address_space(1))) void*)g,
                                   (__attribute__((address_space(3))) void*)l, 16, 0, 0);
}

// read one 16B MFMA fragment from a 128B-row LDS tile with XOR swizzle
__device__ __forceinline__ bf16x8 lds_frag(const char* base, int row, int bir) {
  int off = (row << 7) + bir;
  off ^= (row & 7) << 4;
  return *(const bf16x8*)(base + off);
}

// pack two f32 to packed bf16 (lo = a, hi = b), RTNE
__device__ __forceinline__ int cvtpk_bf16(float a, float b) {
  int r; asm("v_cvt_pk_bf16_f32 %0, %1, %2" : "=v"(r) : "v"(a), "v"(b)); return r;
}

// swap a's upper-lane-half with b's lower-lane-half (v_permlane32_swap_b32)
__device__ __forceinline__ void plswap(int& a, int& b) {
#if __has_builtin(__builtin_amdgcn_permlane32_swap)
  i32x2 r = __builtin_amdgcn_permlane32_swap(a, b, false, false);
  a = r[0]; b = r[1];
#else
  asm volatile("s_nop 1\n\tv_permlane32_swap_b32 %0, %1" : "+v"(a), "+v"(b));
#endif
}

// ---------------- elementwise fp32 -> bf16 ----------------
__global__ __launch_bounds__(256) void k_cvt(const float* __restrict__ src,
                                             unsigned short* __restrict__ dst, int n) {
  int i = (blockIdx.x * 256 + threadIdx.x) * 8;
  if (i >= n) return;
  fl4 a = *(const fl4*)(src + i);
  fl4 b = *(const fl4*)(src + i + 4);
  u16x8 o;
  o[0] = f2bf_bits(a[0]); o[1] = f2bf_bits(a[1]); o[2] = f2bf_bits(a[2]); o[3] = f2bf_bits(a[3]);
  o[4] = f2bf_bits(b[0]); o[5] = f2bf_bits(b[1]); o[6] = f2bf_bits(b[2]); o[7] = f2bf_bits(b[3]);
  *(u16x8*)(dst + i) = o;
}

// ---------------- transpose + convert, both weights in one launch ----------------
// blockIdx.x < 48: W_qkv [1024][3072] -> [3072][1024]; else W_proj [1024][1024] -> [1024][1024]
__global__ __launch_bounds__(256) void k_tcvt2(const float* __restrict__ wqkv,
                                               unsigned short* __restrict__ dqkv,
                                               const float* __restrict__ wproj,
                                               unsigned short* __restrict__ dproj) {
  __shared__ float tile[64][65];
  const int bx = blockIdx.x;
  const float* src; unsigned short* dst; int NCOL, nt;
  if (bx < 48) { src = wqkv; dst = dqkv; NCOL = 3072; nt = bx * 64; }
  else         { src = wproj; dst = dproj; NCOL = 1024; nt = (bx - 48) * 64; }
  const int kt = blockIdx.y * 64;
  const int t = threadIdx.x;
  {
    int r = t >> 2, c0 = (t & 3) * 16;
    const float* s = src + (size_t)(kt + r) * NCOL + nt + c0;
    #pragma unroll
    for (int j = 0; j < 4; ++j) {
      fl4 v = *(const fl4*)(s + j * 4);
      tile[r][c0 + j * 4 + 0] = v[0]; tile[r][c0 + j * 4 + 1] = v[1];
      tile[r][c0 + j * 4 + 2] = v[2]; tile[r][c0 + j * 4 + 3] = v[3];
    }
  }
  __syncthreads();
  {
    int n = t >> 2, kc = (t & 3) * 16;
    unsigned short* d = dst + (size_t)(nt + n) * 1024 + kt + kc;
    u16x8 o0, o1;
    #pragma unroll
    for (int j = 0; j < 8; ++j) o0[j] = f2bf_bits(tile[kc + j][n]);
    #pragma unroll
    for (int j = 0; j < 8; ++j) o1[j] = f2bf_bits(tile[kc + 8 + j][n]);
    *(u16x8*)d = o0;
    *(u16x8*)(d + 8) = o1;
  }
}

// ---------------- bf16 GEMM: C[M][Ncols] = A[M][1024] * Bt[Ncols][1024]^T ----------------
template <int MODE>
__global__ __launch_bounds__(256) void k_gemm(const unsigned short* __restrict__ A,
                                              const unsigned short* __restrict__ Bt,
                                              unsigned short* __restrict__ qp,
                                              unsigned short* __restrict__ kp,
                                              unsigned short* __restrict__ vtp,
                                              const float* __restrict__ bias,
                                              float* __restrict__ outp) {
  __shared__ char lA[16384], lB[16384];
  const int tid = threadIdx.x, lane = tid & 63, w = tid >> 6;
  const int wm = w >> 1, wn = w & 1;
  const int m0 = blockIdx.y * 128, n0 = blockIdx.x * 128;
  const char* Ab = (const char*)A + (size_t)m0 * 2048;
  const char* Bb = (const char*)Bt + (size_t)n0 * 2048;

  f32x4 acc[4][4];
  #pragma unroll
  for (int mi = 0; mi < 4; ++mi)
    #pragma unroll
    for (int ni = 0; ni < 4; ++ni) acc[mi][ni] = f32x4{0.f, 0.f, 0.f, 0.f};

  for (int kt = 0; kt < 16; ++kt) {
    #pragma unroll
    for (int i = 0; i < 4; ++i) {
      int c = i * 256 + tid;
      int row = c >> 3, cc = c & 7, ccs = cc ^ (row & 7);
      char* dstA = lA + (i * 256 + w * 64) * 16;
      char* dstB = lB + (i * 256 + w * 64) * 16;
      gload_lds16(Ab + (size_t)row * 2048 + kt * 128 + ccs * 16, dstA);
      gload_lds16(Bb + (size_t)row * 2048 + kt * 128 + ccs * 16, dstB);
    }
    __syncthreads();
    #pragma unroll
    for (int ks = 0; ks < 2; ++ks) {
      bf16x8 af[4], bfv[4];
      #pragma unroll
      for (int mi = 0; mi < 4; ++mi)
        af[mi] = lds_frag(lA, wm * 64 + mi * 16 + (lane & 15), ks * 64 + ((lane >> 4) << 4));
      #pragma unroll
      for (int ni = 0; ni < 4; ++ni)
        bfv[ni] = lds_frag(lB, wn * 64 + ni * 16 + (lane & 15), ks * 64 + ((lane >> 4) << 4));
      #pragma unroll
      for (int mi = 0; mi < 4; ++mi)
        #pragma unroll
        for (int ni = 0; ni < 4; ++ni)
          acc[mi][ni] = MFMA16(af[mi], bfv[ni], acc[mi][ni]);
    }
    __syncthreads();
  }

  if (MODE == 0) {
    #pragma unroll
    for (int mi = 0; mi < 4; ++mi) {
      int row0 = m0 + wm * 64 + mi * 16 + ((lane >> 4) << 2);
      int bb = row0 >> 10, nn0 = row0 & 1023;
      #pragma unroll
      for (int ni = 0; ni < 4; ++ni) {
        int col = n0 + wn * 64 + ni * 16 + (lane & 15);
        int tt = col >> 10, rem = col & 1023, h = rem >> 6, d = rem & 63;
        f32x4 a = acc[mi][ni];
        if (tt == 2) {
          u16x4 pv;
          pv[0] = f2bf_bits(a[0]); pv[1] = f2bf_bits(a[1]);
          pv[2] = f2bf_bits(a[2]); pv[3] = f2bf_bits(a[3]);
          *(u16x4*)(vtp + (((size_t)(bb * 16 + h) * 64 + d) << 10) + nn0) = pv;
        } else {
          unsigned short* dst = (tt == 0) ? qp : kp;
          size_t base = ((size_t)(bb * 16 + h)) << 16;
          #pragma unroll
          for (int r = 0; r < 4; ++r)
            dst[base + (size_t)(nn0 + r) * 64 + d] = f2bf_bits(a[r]);
        }
      }
    }
  } else {
    #pragma unroll
    for (int mi = 0; mi < 4; ++mi) {
      int row0 = m0 + wm * 64 + mi * 16 + ((lane >> 4) << 2);
      #pragma unroll
      for (int ni = 0; ni < 4; ++ni) {
        int col = n0 + wn * 64 + ni * 16 + (lane & 15);
        float bv = bias[col];
        f32x4 a = acc[mi][ni];
        #pragma unroll
        for (int r = 0; r < 4; ++r)
          outp[(size_t)(row0 + r) * 1024 + col] = a[r] + bv;
      }
    }
  }
}

// ---------------- flash attention: 8-wave blocks, 3-buffer counted-vmcnt pipeline ----------------
// 512 blocks = 64 heads x 8 q-chunks (128 rows). 8 waves = 4 q-subchunks x 2 key-pairs
// (pair 0: keys 0-511, pair 1: keys 512-1023). Per step one shared 16KB K/V tile (both pairs)
// feeds all 8 waves. 3 LDS buffers; step t: vmcnt(2) [wait only t's own 2 loads; t+1's stay
// in flight] -> s_barrier -> STAGE(t+2) -> compute(t). Mask via rank-1 bias MFMA, all mask
// loads hoisted (bws[16], fully unrolled). Partials combined via LDS at the end.
// Buffer layout (16KB): [KA 4K][KB 4K][VA 4K][VB 4K]
//   K tile: 32 rows x 128B, slot s at row r holds global chunk s^(r&7)
//   V tile: 64 rows x 64B,  slot s at row r holds global chunk s^((r>>1)&3)
__global__ __launch_bounds__(512, 4) void k_attn(const unsigned short* __restrict__ qp,
                                                 const unsigned short* __restrict__ kp,
                                                 const unsigned short* __restrict__ vtp,
                                                 const float* __restrict__ mask,
                                                 unsigned short* __restrict__ aop) {
  __shared__ __align__(16) char lds[49152];
  const int tid = threadIdx.x, lane = tid & 63, w = tid >> 6;
  const int hi = lane >> 5, lq = lane & 31;
  const int pair = w >> 2, qsub = w & 3;
  // XCD swizzle: all 8 q-chunk blocks of a head on one XCD; 8 heads/XCD (~3MB < 4MB L2)
  const int g = blockIdx.x;
  const int bh = (g & 7) * 8 + ((g >> 6) & 7);
  const int qc = (g >> 3) & 7;
  const int b = bh >> 4, h = bh & 15;
  const char* kb = (const char*)(kp + ((size_t)bh << 16));
  const char* vb = (const char*)(vtp + ((size_t)bh << 16));
  const unsigned short* qh = qp + ((size_t)bh << 16);
  const float* mrow = mask + b * 1024 + pair * 512;
  const int q0 = qc * 128 + qsub * 32;

  // ---- staging addresses: thread covers K chunk tid and V chunk tid (512 each) ----
  const int kpk = tid >> 8, krow = (tid >> 3) & 31, kslot = tid & 7;
  const char* gK = kb + (size_t)kpk * 65536 + (size_t)krow * 128
                   + ((kslot ^ (krow & 7)) * 16);                    // + t*4096
  const int vpk = tid >> 8, vrow = (tid >> 2) & 63, vslot = tid & 3;
  const char* gV = vb + (size_t)vpk * 1024 + (size_t)vrow * 2048
                   + ((vslot ^ ((vrow >> 1) & 3)) * 16);             // + t*64
  char* const dK = lds + tid * 16;          // + buf*16384
  char* const dV = lds + 8192 + tid * 16;   // + buf*16384

  // ---- hoisted fragment-read offsets (within pair's 4KB region) ----
  int kfo[4], vfo[4];
  #pragma unroll
  for (int dc = 0; dc < 4; ++dc)
    kfo[dc] = lq * 128 + (((dc << 1) | hi) ^ (lq & 7)) * 16;
  #pragma unroll
  for (int ks = 0; ks < 2; ++ks)
    #pragma unroll
    for (int nb = 0; nb < 2; ++nb) {
      int row = nb * 32 + lq;
      vfo[ks * 2 + nb] = row * 64 + (((ks << 1) | hi) ^ ((row >> 1) & 3)) * 16;
    }

  // ---- hoist ALL mask loads: bias-MFMA A-words per step ((1-mask)*(-40), exact 0 if mask==1)
  int bws[16];
  #pragma unroll
  for (int t2 = 0; t2 < 16; ++t2) {
    float mv = mrow[t2 * 32 + lq];
    bws[t2] = (hi == 0) ? (int)f2bf_bits((1.0f - mv) * -40.0f) : 0;
  }

  // Q B-frags: B[kd = dc*16 + hi*8 + j][q = lq]
  bf16x8 qB[4];
  #pragma unroll
  for (int dc = 0; dc < 4; ++dc)
    qB[dc] = *(const bf16x8*)(qh + (q0 + lq) * 64 + dc * 16 + hi * 8);

  // ones B-frag for the bias MFMA: B[0][q] = 1
  i32x4 onesw = {hi == 0 ? 0x3F80 : 0, 0, 0, 0};
  const bf16x8 onesB = __builtin_bit_cast(bf16x8, onesw);

  f32x16 O0, O1;
  #pragma unroll
  for (int i = 0; i < 16; ++i) { O0[i] = 0.f; O1[i] = 0.f; }
  float lsum = 0.f;

#define STAGE(BUF, T)                                                          \
  do {                                                                         \
    gload_lds16(gK + (T) * 4096, dK + (BUF) * 16384);                          \
    gload_lds16(gV + (T) * 64,   dV + (BUF) * 16384);                          \
  } while (0)

#define VMCNT(N) asm volatile("s_waitcnt vmcnt(" #N ")" ::: "memory")

#define STEP(BUF, T, N)                                                        \
  do {                                                                         \
    VMCNT(N);                                                                  \
    __builtin_amdgcn_s_barrier();                                              \
    if ((T) + 2 <= 15) STAGE(((T) + 2) % 3, (T) + 2);                          \
    const char* K = lds + (BUF) * 16384 + pair * 4096;                         \
    const char* V = lds + (BUF) * 16384 + 8192 + pair * 4096;                  \
    f32x16 acc;                                                                \
    _Pragma("unroll") for (int i = 0; i < 16; ++i) acc[i] = 0.f;               \
    __builtin_amdgcn_s_setprio(1);                                             \
    _Pragma("unroll") for (int dc = 0; dc < 4; ++dc) {                         \
      bf16x8 kf = *(const bf16x8*)(K + kfo[dc]);                               \
      acc = MFMA32(kf, qB[dc], acc);                                           \
    }                                                                          \
    __builtin_amdgcn_s_setprio(0);                                             \
    {                                                                          \
      i32x4 bwv = {bws[T], 0, 0, 0};                                           \
      acc = MFMA32(__builtin_bit_cast(bf16x8, bwv), onesB, acc);               \
    }                                                                          \
    float p[16];                                                               \
    _Pragma("unroll") for (int r = 0; r < 16; ++r) {                           \
      p[r] = exp2f(fmaf(acc[r], 0.18033688f, -5.7707802f));                    \
      lsum += p[r];                                                            \
    }                                                                          \
    int X0 = cvtpk_bf16(p[0], p[1]),   X1 = cvtpk_bf16(p[2], p[3]);            \
    int Y0 = cvtpk_bf16(p[4], p[5]),   Y1 = cvtpk_bf16(p[6], p[7]);            \
    int Z0 = cvtpk_bf16(p[8], p[9]),   Z1 = cvtpk_bf16(p[10], p[11]);          \
    int W0 = cvtpk_bf16(p[12], p[13]), W1 = cvtpk_bf16(p[14], p[15]);          \
    plswap(X0, Y0); plswap(X1, Y1);                                            \
    plswap(Z0, W0); plswap(Z1, W1);                                            \
    i32x4 pa0v = {X0, X1, Y0, Y1};                                             \
    i32x4 pa1v = {Z0, Z1, W0, W1};                                             \
    const bf16x8 PA0 = __builtin_bit_cast(bf16x8, pa0v);                       \
    const bf16x8 PA1 = __builtin_bit_cast(bf16x8, pa1v);                       \
    bf16x8 va0 = *(const bf16x8*)(V + vfo[0]);                                 \
    bf16x8 va1 = *(const bf16x8*)(V + vfo[1]);                                 \
    bf16x8 vb0 = *(const bf16x8*)(V + vfo[2]);                                 \
    bf16x8 vb1 = *(const bf16x8*)(V + vfo[3]);                                 \
    __builtin_amdgcn_s_setprio(1);                                             \
    O0 = MFMA32(PA0, va0, O0);                                                 \
    O1 = MFMA32(PA0, va1, O1);                                                 \
    O0 = MFMA32(PA1, vb0, O0);                                                 \
    O1 = MFMA32(PA1, vb1, O1);                                                 \
    __builtin_amdgcn_s_setprio(0);                                             \
  } while (0)

  STAGE(0, 0);
  STAGE(1, 1);
  STEP(0, 0, 2);  STEP(1, 1, 2);  STEP(2, 2, 2);  STEP(0, 3, 2);
  STEP(1, 4, 2);  STEP(2, 5, 2);  STEP(0, 6, 2);  STEP(1, 7, 2);
  STEP(2, 8, 2);  STEP(0, 9, 2);  STEP(1, 10, 2); STEP(2, 11, 2);
  STEP(0, 12, 2); STEP(1, 13, 2); STEP(2, 14, 2); STEP(0, 15, 0);
#undef STEP
#undef VMCNT
#undef STAGE

  // ---- combine the two key-halves through LDS, then normalize + store ----
  __syncthreads();
  float tot = lsum + __shfl_xor(lsum, 32);
  float* fx = (float*)lds;
  if (pair == 1) {
    int base = qsub * 64 * 34 + lane * 34;
    #pragma unroll
    for (int r = 0; r < 16; ++r) { fx[base + r] = O0[r]; fx[base + 16 + r] = O1[r]; }
    fx[base + 32] = tot;
  }
  __syncthreads();
  if (pair == 0) {
    int base = qsub * 64 * 34 + lane * 34;
    float invT = 1.0f / (tot + fx[base + 32]);
    #pragma unroll
    for (int r = 0; r < 16; ++r) {
      int qr = (r & 3) + 8 * (r >> 2) + 4 * hi;
      float iv = __shfl(invT, qr);
      float o0 = (O0[r] + fx[base + r]) * iv;
      float o1 = (O1[r] + fx[base + 16 + r]) * iv;
      size_t ob = (size_t)(b * 1024 + q0 + qr) * 1024 + h * 64 + lq;
      aop[ob] = f2bf_bits(o0);
      aop[ob + 32] = f2bf_bits(o1);
    }
  }
}

extern "C" void kernel_launch(void* const* d_in, const int* in_sizes, int n_in,
                              void* d_out, int out_size, void* d_ws, size_t ws_size,
                              hipStream_t stream) {
  const float* x     = (const float*)d_in[0];
  const float* mask  = (const float*)d_in[1];
  const float* wqkv  = (const float*)d_in[2];
  const float* wproj = (const float*)d_in[3];
  const float* bproj = (const float*)d_in[4];
  float* out = (float*)d_out;

  char* ws = (char*)d_ws;
  unsigned short* xb     = (unsigned short*)(ws);                 //  8 MB  x bf16 [4096][1024]
  unsigned short* wqkvt  = (unsigned short*)(ws + 8388608);       //  6 MB  W_qkv^T bf16 [3072][1024]
  unsigned short* wprojt = (unsigned short*)(ws + 14680064);      //  2 MB  W_proj^T bf16 [1024][1024]
  unsigned short* qbuf   = (unsigned short*)(ws + 16777216);      //  8 MB  q [B,H,N,D]
  unsigned short* kbuf   = (unsigned short*)(ws + 25165824);      //  8 MB  k [B,H,N,D]
  unsigned short* vtbuf  = (unsigned short*)(ws + 33554432);      //  8 MB  v^T [B,H,D,N]
  unsigned short* aobuf  = (unsigned short*)(ws + 41943040);      //  8 MB  attn out bf16 [4096][1024]

  k_cvt<<<dim3(2048), dim3(256), 0, stream>>>(x, xb, 4194304);
  k_tcvt2<<<dim3(64, 16), dim3(256), 0, stream>>>(wqkv, wqkvt, wproj, wprojt);
  k_gemm<0><<<dim3(24, 32), dim3(256), 0, stream>>>(xb, wqkvt, qbuf, kbuf, vtbuf, nullptr, nullptr);
  k_attn<<<dim3(512), dim3(512), 0, stream>>>(qbuf, kbuf, vtbuf, mask, aobuf);
  k_gemm<1><<<dim3(8, 32), dim3(256), 0, stream>>>(aobuf, wprojt, nullptr, nullptr, nullptr, bproj, out);
}